// Round 8
// baseline (686.647 us; speedup 1.0000x reference)
//
#include <hip/hip_runtime.h>
#include <stdint.h>

#define UNITS 64
#define UU 4096          // UNITS*UNITS
#define NG 50
#define NSLOT 51         // 50 gaussians + 1 bias slot
#define GAMMA_C 10.0f
#define STEP_C (30.0f / 49.0f)
#define NWIN 4           // gaussian window width (centers lo..lo+3)
#define NSL 5            // NWIN + bias slot
#define GRIDB 1024       // persistent-kernel grid: 4 blocks/CU * 256 CU

typedef __attribute__((ext_vector_type(8))) short bf16x8;
typedef __attribute__((ext_vector_type(4))) float f32x4;

__device__ __forceinline__ float bf_lo(uint32_t u) { return __uint_as_float(u << 16); }
__device__ __forceinline__ float bf_hi(uint32_t u) { return __uint_as_float(u & 0xffff0000u); }
__device__ __forceinline__ float bfu(uint16_t v) { return __uint_as_float(((uint32_t)v) << 16); }
__device__ __forceinline__ uint16_t f2bf(float x) {
  uint32_t u = __float_as_uint(x);
  u += 0x7fffu + ((u >> 16) & 1u);           // RNE to bf16
  return (uint16_t)(u >> 16);
}
__device__ __forceinline__ uint32_t pk_bf16(float lo, float hi) {
  uint32_t r;
  asm("v_cvt_pk_bf16_f32 %0, %1, %2" : "=v"(r) : "v"(lo), "v"(hi));
  return r;
}

// Device-scope grid barrier. Requires all gridDim.x blocks co-resident
// (guaranteed: __launch_bounds__(256,4) -> VGPR<=128 -> 4 blocks/CU, 0 LDS,
// grid=1024 on 256 CUs). bar[k] zeroed via hipMemsetAsync before each launch.
__device__ __forceinline__ void gbar(int* bar, int k, int nblk) {
  __syncthreads();
  if (threadIdx.x == 0) {
    __threadfence();                         // release: prior writes visible
    atomicAdd(&bar[k], 1);
    while (atomicAdd(&bar[k], 0) < nblk) __builtin_amdgcn_s_sleep(2);
  }
  __syncthreads();
  __threadfence();                           // acquire
}

// ===== Fused whole-pipeline persistent kernel =====
__global__ void __launch_bounds__(256, 4) k_all(
    const float* __restrict__ nf, const int* __restrict__ ei,
    const float* __restrict__ dist,
    const float* __restrict__ W1, const float* __restrict__ b1,
    const float* __restrict__ W2, const float* __restrict__ b2,
    const float* __restrict__ Wt,
    float* __restrict__ A, uint16_t* __restrict__ T5B,
    uint16_t* __restrict__ nfb, uint16_t* __restrict__ Ybf,
    float* __restrict__ msg, float* __restrict__ out,
    int* __restrict__ bar, int NN, int E, int n_out) {
  const int tid = blockIdx.x * 256 + threadIdx.x;
  const int NT = gridDim.x * 256;
  const int nblk = gridDim.x;

  // ---- P0: A[g,ij], nf->bf16, zero msg ----
  for (int t = tid; t < NSLOT * UU; t += NT) {
    int g = t >> 12, ij = t & (UU - 1);
    float acc = 0.f;
    if (g < NG) {
      const float* w1r = W1 + g * UNITS;
      #pragma unroll 8
      for (int k = 0; k < UNITS; ++k) acc = fmaf(w1r[k], W2[k * UU + ij], acc);
    } else {
      #pragma unroll 8
      for (int k = 0; k < UNITS; ++k) acc = fmaf(b1[k], W2[k * UU + ij], acc);
      acc += b2[ij];
    }
    A[t] = acc;
  }
  {
    int n4 = n_out >> 2;
    for (int t = tid; t < n4; t += NT) {
      float4 v = reinterpret_cast<const float4*>(nf)[t];
      uint2 p; p.x = pk_bf16(v.x, v.y); p.y = pk_bf16(v.z, v.w);
      reinterpret_cast<uint2*>(nfb)[t] = p;
    }
    float4 z = {0.f, 0.f, 0.f, 0.f};
    for (int t = tid; t < n4; t += NT)
      reinterpret_cast<float4*>(msg)[t] = z;
  }
  gbar(bar, 0, nblk);

  // ---- P1: T5B[g][mb][i][m'] = sum_j A[g,i*64+j] * Wt[mb*8+m', j] ----
  for (int t = tid; t < NSLOT * UU; t += NT) {
    int g = t >> 12, idx = t & (UU - 1);
    int i = idx >> 6, m = idx & 63;
    const float* ar = A + g * UU + i * UNITS;
    const float* wr = Wt + m * UNITS;
    float acc = 0.f;
    #pragma unroll 8
    for (int j = 0; j < UNITS; ++j) acc = fmaf(ar[j], wr[j], acc);
    T5B[(((g << 3) + (m >> 3)) << 9) + (i << 3) + (m & 7)] = f2bf(acc);
  }
  gbar(bar, 1, nblk);

  // ---- P2: Y[g][n][i] via MFMA, permuted B cols (i = 4*lr + nt) ----
  {
    int w = threadIdx.x >> 6, l = threadIdx.x & 63;
    int lr = l & 15, lg = l >> 4;
    int ntx = (NN + 127) >> 7;               // 79
    int ntiles = ntx * NSLOT;                // 4029
    for (int tile = blockIdx.x; tile < ntiles; tile += nblk) {
      int x = tile % ntx, g = tile / ntx;
      int base = x * 128 + w * 32;

      bf16x8 bfr[2][4];
      const char* bb = (const char*)T5B + (g << 13) + (lg << 10) + (lr << 6);
      #pragma unroll
      for (int kk = 0; kk < 2; ++kk)
        #pragma unroll
        for (int nt = 0; nt < 4; ++nt)
          bfr[kk][nt] = *reinterpret_cast<const bf16x8*>(bb + (kk << 12) + (nt << 4));

      bf16x8 afr[2][2];
      #pragma unroll
      for (int ms = 0; ms < 2; ++ms) {
        int node = base + ms * 16 + lr;
        if (node >= NN) node = NN - 1;       // clamp: garbage rows never stored
        const char* ab = (const char*)nfb + node * 128 + (lg << 4);
        afr[ms][0] = *reinterpret_cast<const bf16x8*>(ab);
        afr[ms][1] = *reinterpret_cast<const bf16x8*>(ab + 64);
      }

      f32x4 acc[2][4] = {};
      #pragma unroll
      for (int ms = 0; ms < 2; ++ms)
        #pragma unroll
        for (int kk = 0; kk < 2; ++kk)
          #pragma unroll
          for (int nt = 0; nt < 4; ++nt)
            acc[ms][nt] = __builtin_amdgcn_mfma_f32_16x16x32_bf16(afr[ms][kk], bfr[kk][nt],
                                                                  acc[ms][nt], 0, 0, 0);

      #pragma unroll
      for (int ms = 0; ms < 2; ++ms) {
        #pragma unroll
        for (int q = 0; q < 4; ++q) {
          int node = base + ms * 16 + lg * 4 + q;
          if (node < NN) {
            uint2 p;
            p.x = pk_bf16(acc[ms][0][q], acc[ms][1][q]);
            p.y = pk_bf16(acc[ms][2][q], acc[ms][3][q]);
            uint16_t* yrow = Ybf + (((size_t)g * NN + node) << 6);
            *reinterpret_cast<uint2*>(yrow + 4 * lr) = p;
          }
        }
      }
    }
  }
  gbar(bar, 2, nblk);

  // ---- P3: edges — 2 per wave, 5 row-gathers + scatter-atomic ----
  {
    int w = threadIdx.x >> 6, lane = threadIdx.x & 63;
    int wv = blockIdx.x * 4 + w;             // 4096 waves
    size_t gstride = (size_t)NN << 6;
    int pairs = (E + 1) >> 1;
    for (int ep = wv; ep < pairs; ep += nblk * 4) {
      #pragma unroll
      for (int p = 0; p < 2; ++p) {
        int e = ep * 2 + p;
        if (e >= E) break;
        int src = ei[e], dst = ei[E + e];
        float d = dist[e];
        int lo = (int)floorf(d * (1.0f / STEP_C)) - 1;
        lo = min(max(lo, 0), NG - NWIN);
        const uint16_t* yb = Ybf + ((size_t)src << 6) + lane;
        float tot = bfu(yb[(size_t)NG * gstride]);        // bias slot, weight 1
        #pragma unroll
        for (int l = 0; l < NWIN; ++l) {
          float t = d - (float)(lo + l) * STEP_C;
          float dfv = __expf(-GAMMA_C * t * t);
          tot = fmaf(dfv, bfu(yb[(size_t)(lo + l) * gstride]), tot);
        }
        atomicAdd(&msg[dst * UNITS + lane], tot);
      }
    }
  }
  gbar(bar, 3, nblk);

  // ---- P4: out = softplus(msg) - ln(2) ----
  {
    int n4 = n_out >> 2;
    for (int t = tid; t < n4; t += NT) {
      float4 x = reinterpret_cast<const float4*>(msg)[t];
      float4 r;
      r.x = ((x.x > 0.f) ? (x.x + log1pf(__expf(-x.x))) : log1pf(__expf(x.x))) - 0.69314718056f;
      r.y = ((x.y > 0.f) ? (x.y + log1pf(__expf(-x.y))) : log1pf(__expf(x.y))) - 0.69314718056f;
      r.z = ((x.z > 0.f) ? (x.z + log1pf(__expf(-x.z))) : log1pf(__expf(x.z))) - 0.69314718056f;
      r.w = ((x.w > 0.f) ? (x.w + log1pf(__expf(-x.w))) : log1pf(__expf(x.w))) - 0.69314718056f;
      reinterpret_cast<float4*>(out)[t] = r;
    }
  }
}

// ===== Fallback path (round-3 structure) if ws can't hold Y =====
__global__ void k_precompA_f(const float* __restrict__ W1, const float* __restrict__ b1,
                             const float* __restrict__ W2, const float* __restrict__ b2,
                             float* __restrict__ A) {
  int ij = blockIdx.x * 256 + threadIdx.x;
  int g = blockIdx.y;
  float acc = 0.f;
  if (g < NG) {
    const float* w1r = W1 + g * UNITS;
    #pragma unroll 8
    for (int k = 0; k < UNITS; ++k) acc = fmaf(w1r[k], W2[k * UU + ij], acc);
  } else {
    #pragma unroll 8
    for (int k = 0; k < UNITS; ++k) acc = fmaf(b1[k], W2[k * UU + ij], acc);
    acc += b2[ij];
  }
  A[g * UU + ij] = acc;
}

__global__ void k_precompT5_f(const float* __restrict__ A, const float* __restrict__ Wt,
                              uint16_t* __restrict__ T5B) {
  int idx = blockIdx.x * 256 + threadIdx.x;
  int g = blockIdx.y;
  int i = idx >> 6, m = idx & 63;
  const float* ar = A + g * UU + i * UNITS;
  const float* wr = Wt + m * UNITS;
  float acc = 0.f;
  #pragma unroll 8
  for (int j = 0; j < UNITS; ++j) acc = fmaf(ar[j], wr[j], acc);
  T5B[(((g << 3) + (m >> 3)) << 9) + (i << 3) + (m & 7)] = f2bf(acc);
}

#define ACC2(u, n0, n1) { a = fmaf(bf_lo(u), (n0), a); a = fmaf(bf_hi(u), (n1), a); }

__global__ void __launch_bounds__(256, 6) k_edge_f(
    const float* __restrict__ nf, const int* __restrict__ ei,
    const float* __restrict__ dist, const uint16_t* __restrict__ T5B,
    float* __restrict__ msg, int E) {
  __shared__ float nfs[4][UNITS];
  int w = threadIdx.x >> 6, lane = threadIdx.x & 63;
  int e = blockIdx.x * 4 + w;
  if (e >= E) return;
  int src = ei[e];
  int dst = ei[E + e];
  float d = dist[e];
  nfs[w][lane] = nf[src * UNITS + lane];
  int lo = (int)floorf(d * (1.0f / STEP_C)) - 1;
  lo = min(max(lo, 0), NG - NWIN);
  float df[NSL];
  #pragma unroll
  for (int l = 0; l < NWIN; ++l) {
    float t = d - (float)(lo + l) * STEP_C;
    df[l] = __expf(-GAMMA_C * t * t);
  }
  df[NWIN] = 1.0f;
  uint32_t off[NSL];
  #pragma unroll
  for (int l = 0; l < NSL; ++l) {
    int gg = (l < NWIN) ? (lo + l) : NG;
    off[l] = (uint32_t)((gg << 13) + (lane << 4));
  }
  const char* base = (const char*)T5B;
  float acc[NSL] = {0.f, 0.f, 0.f, 0.f, 0.f};
  #pragma unroll
  for (int mb = 0; mb < 8; ++mb) {
    float4 n0 = *reinterpret_cast<const float4*>(&nfs[w][mb * 8]);
    float4 n1 = *reinterpret_cast<const float4*>(&nfs[w][mb * 8 + 4]);
    #pragma unroll
    for (int l = 0; l < NSL; ++l) {
      uint4 u = *reinterpret_cast<const uint4*>(base + off[l] + (mb << 10));
      float a = acc[l];
      ACC2(u.x, n0.x, n0.y)
      ACC2(u.y, n0.z, n0.w)
      ACC2(u.z, n1.x, n1.y)
      ACC2(u.w, n1.z, n1.w)
      acc[l] = a;
    }
  }
  float tot = 0.f;
  #pragma unroll
  for (int l = 0; l < NSL; ++l) tot = fmaf(df[l], acc[l], tot);
  atomicAdd(&msg[dst * UNITS + lane], tot);
}

__global__ void k_final_f(const float* __restrict__ msg, float* __restrict__ out, int n) {
  int i = blockIdx.x * 256 + threadIdx.x;
  if (i >= n) return;
  float x = msg[i];
  float sp = (x > 0.f) ? (x + log1pf(__expf(-x))) : log1pf(__expf(x));
  out[i] = sp - 0.69314718056f;
}

extern "C" void kernel_launch(void* const* d_in, const int* in_sizes, int n_in,
                              void* d_out, int out_size, void* d_ws, size_t ws_size,
                              hipStream_t stream) {
  const float* nf   = (const float*)d_in[0];
  const int*   ei   = (const int*)d_in[1];
  const float* dist = (const float*)d_in[2];
  const float* W1   = (const float*)d_in[3];
  const float* b1   = (const float*)d_in[4];
  const float* W2   = (const float*)d_in[5];
  const float* b2   = (const float*)d_in[6];
  const float* Wt   = (const float*)d_in[7];
  float* out = (float*)d_out;

  int E = in_sizes[2];               // 50000
  int NN = in_sizes[0] / UNITS;      // 10000
  int n_out = out_size;              // NN * UNITS

  // workspace layout
  char* ws = (char*)d_ws;
  size_t off_T5  = 835584;                                  // A: 51*4096*4
  size_t off_msg = off_T5 + 417792;                         // T5B: 51*4096*2
  size_t off_nfb = off_msg + (size_t)n_out * 4;             // msg
  size_t off_Y   = off_nfb + (size_t)n_out * 2;             // nfb
  size_t off_bar = off_Y + (size_t)NSLOT * NN * UNITS * 2;  // Ybf: ~65.3 MB
  size_t need    = off_bar + 64;                            // 4 barrier counters

  float*    A   = (float*)ws;
  uint16_t* T5B = (uint16_t*)(ws + off_T5);
  float*    msg = (float*)(ws + off_msg);

  if (ws_size >= need) {
    uint16_t* nfb = (uint16_t*)(ws + off_nfb);
    uint16_t* Ybf = (uint16_t*)(ws + off_Y);
    int*      bar = (int*)(ws + off_bar);
    hipMemsetAsync(bar, 0, 64, stream);      // reset barriers each replay (in-graph)
    k_all<<<GRIDB, 256, 0, stream>>>(nf, ei, dist, W1, b1, W2, b2, Wt,
                                     A, T5B, nfb, Ybf, msg, out, bar, NN, E, n_out);
  } else {
    hipMemsetAsync(msg, 0, (size_t)n_out * sizeof(float), stream);
    k_precompA_f <<<dim3(16, NSLOT), 256, 0, stream>>>(W1, b1, W2, b2, A);
    k_precompT5_f<<<dim3(16, NSLOT), 256, 0, stream>>>(A, Wt, T5B);
    k_edge_f     <<<(E + 3) / 4, 256, 0, stream>>>(nf, ei, dist, T5B, msg, E);
    k_final_f    <<<(n_out + 255) / 256, 256, 0, stream>>>(msg, out, n_out);
  }
}

// Round 9
// 167.553 us; speedup vs baseline: 4.0981x; 4.0981x over previous
//
#include <hip/hip_runtime.h>
#include <stdint.h>

#define UNITS 64
#define UU 4096          // UNITS*UNITS
#define NG 50
#define NSLOT 51         // 50 gaussians + 1 bias slot
#define GAMMA_C 10.0f
#define STEP_C (30.0f / 49.0f)
#define NWIN 4           // gaussian window width (centers lo..lo+3)
#define NSL 5            // NWIN + bias slot

typedef __attribute__((ext_vector_type(8))) short bf16x8;
typedef __attribute__((ext_vector_type(4))) float f32x4;

__device__ __forceinline__ float bf_lo(uint32_t u) { return __uint_as_float(u << 16); }
__device__ __forceinline__ float bf_hi(uint32_t u) { return __uint_as_float(u & 0xffff0000u); }
__device__ __forceinline__ float bfu(uint16_t v) { return __uint_as_float(((uint32_t)v) << 16); }
__device__ __forceinline__ uint16_t f2bf(float x) {
  uint32_t u = __float_as_uint(x);
  u += 0x7fffu + ((u >> 16) & 1u);           // RNE to bf16
  return (uint16_t)(u >> 16);
}
__device__ __forceinline__ uint32_t pk_bf16(float lo, float hi) {
  uint32_t r;
  asm("v_cvt_pk_bf16_f32 %0, %1, %2" : "=v"(r) : "v"(lo), "v"(hi));
  return r;
}

// ===== k_w: fused filter-weight precompute =====
// Blocks 0..15: block b owns output rows i in [b*4, b*4+4) (ij in [b*256,(b+1)*256)).
//   Phase A: A[g, ij] into LDS (W2 column read ONCE per ij: 3 MB total vs 53 MB).
//   Phase B: T5B[g][m>>3][i][m&7] = sum_j A[g,i,j]*Wt[m,j], Wt row in 64 regs/lane.
// Blocks 16..79: zero msg.
__global__ void __launch_bounds__(256) k_w(
    const float* __restrict__ W1, const float* __restrict__ b1,
    const float* __restrict__ W2, const float* __restrict__ b2,
    const float* __restrict__ Wt,
    uint16_t* __restrict__ T5B, float* __restrict__ msg, int n_out) {
  int bx = blockIdx.x;
  if (bx >= 16) {
    int n4 = n_out >> 2;
    float4 z = {0.f, 0.f, 0.f, 0.f};
    for (int t = (bx - 16) * 256 + threadIdx.x; t < n4; t += 64 * 256)
      reinterpret_cast<float4*>(msg)[t] = z;
    return;
  }
  __shared__ float Aloc[NSLOT][256];           // 52 KB
  const int t = threadIdx.x;
  const int ij = bx * 256 + t;

  // ---- Phase A: A[g][t] for this block's 256 ij columns ----
  {
    float acc[17];
#define CHUNK(G0, N)                                                        \
    { _Pragma("unroll") for (int q = 0; q < (N); ++q) acc[q] = 0.f;         \
      for (int k = 0; k < UNITS; ++k) {                                     \
        float w2 = W2[k * UU + ij];                                         \
        _Pragma("unroll") for (int q = 0; q < (N); ++q)                     \
          acc[q] = fmaf(W1[((G0) + q) * UNITS + k], w2, acc[q]);            \
      }                                                                     \
      _Pragma("unroll") for (int q = 0; q < (N); ++q) Aloc[(G0) + q][t] = acc[q]; }
    CHUNK(0, 17)
    CHUNK(17, 17)
    CHUNK(34, 16)
#undef CHUNK
    float ab = 0.f;
    for (int k = 0; k < UNITS; ++k) ab = fmaf(b1[k], W2[k * UU + ij], ab);
    Aloc[NG][t] = ab + b2[ij];                 // bias slot
  }
  __syncthreads();

  // ---- Phase B: T5 rows for i = bx*4 + i_local ----
  const int i_local = t >> 6, m = t & 63;
  float wt[64];
  {
    const float4* wtr = reinterpret_cast<const float4*>(Wt + m * UNITS);
    #pragma unroll
    for (int q = 0; q < 16; ++q) {
      float4 v = wtr[q];
      wt[4 * q] = v.x; wt[4 * q + 1] = v.y; wt[4 * q + 2] = v.z; wt[4 * q + 3] = v.w;
    }
  }
  const int gi = bx * 4 + i_local;
  for (int g = 0; g < NSLOT; ++g) {
    const float* ar = &Aloc[g][i_local * 64];  // wave-uniform address: LDS broadcast
    float acc = 0.f;
    #pragma unroll 8
    for (int j = 0; j < UNITS; ++j) acc = fmaf(ar[j], wt[j], acc);
    T5B[(((g << 3) + (m >> 3)) << 9) + (gi << 3) + (m & 7)] = f2bf(acc);
  }
}

// ===== k_y: Y[node][g][ch] via MFMA; A-frags loaded once per block (f32->bf16
// in-register), g-loop reuses them. Permuted B cols: tile nt holds col 4*lr+nt,
// so lane stores 4 consecutive channels as one uint2. =====
__global__ void __launch_bounds__(256) k_y(const float* __restrict__ nf,
                                           const uint16_t* __restrict__ T5B,
                                           uint16_t* __restrict__ Ybf, int NN) {
  int w = threadIdx.x >> 6, l = threadIdx.x & 63;
  int lr = l & 15, lg = l >> 4;
  int gy = blockIdx.y;                       // 0..7
  int base = blockIdx.x * 128 + w * 32;

  // A fragments: lane l, row = node, k = kk*32 + lg*8 + j  (from f32, cvt here)
  union { bf16x8 v; uint32_t u[4]; } afr[2][2];
  #pragma unroll
  for (int ms = 0; ms < 2; ++ms) {
    int node = base + ms * 16 + lr;
    if (node >= NN) node = NN - 1;           // clamp: garbage rows never stored
    const float4* ab = reinterpret_cast<const float4*>(nf + node * UNITS) + lg * 2;
    #pragma unroll
    for (int kk = 0; kk < 2; ++kk) {
      float4 v0 = ab[kk * 8], v1 = ab[kk * 8 + 1];
      afr[ms][kk].u[0] = pk_bf16(v0.x, v0.y);
      afr[ms][kk].u[1] = pk_bf16(v0.z, v0.w);
      afr[ms][kk].u[2] = pk_bf16(v1.x, v1.y);
      afr[ms][kk].u[3] = pk_bf16(v1.z, v1.w);
    }
  }

  for (int g = gy; g < NSLOT; g += 8) {
    bf16x8 bfr[2][4];
    const char* bb = (const char*)T5B + (g << 13) + (lg << 10) + (lr << 6);
    #pragma unroll
    for (int kk = 0; kk < 2; ++kk)
      #pragma unroll
      for (int nt = 0; nt < 4; ++nt)
        bfr[kk][nt] = *reinterpret_cast<const bf16x8*>(bb + (kk << 12) + (nt << 4));

    f32x4 acc[2][4] = {};
    #pragma unroll
    for (int ms = 0; ms < 2; ++ms)
      #pragma unroll
      for (int kk = 0; kk < 2; ++kk)
        #pragma unroll
        for (int nt = 0; nt < 4; ++nt)
          acc[ms][nt] = __builtin_amdgcn_mfma_f32_16x16x32_bf16(afr[ms][kk].v, bfr[kk][nt],
                                                                acc[ms][nt], 0, 0, 0);

    #pragma unroll
    for (int ms = 0; ms < 2; ++ms) {
      #pragma unroll
      for (int q = 0; q < 4; ++q) {
        int node = base + ms * 16 + lg * 4 + q;
        if (node < NN) {
          uint2 p;
          p.x = pk_bf16(acc[ms][0][q], acc[ms][1][q]);
          p.y = pk_bf16(acc[ms][2][q], acc[ms][3][q]);
          uint16_t* yrow = Ybf + ((size_t)node * NSLOT + g) * UNITS;
          *reinterpret_cast<uint2*>(yrow + 4 * lr) = p;
        }
      }
    }
  }
}

// ===== k_e: 4 edges/wave; Y[node][g][ch] makes the 4 window reads 512B
// contiguous (+ adjacent bias row). =====
__global__ void __launch_bounds__(256) k_e(const int* __restrict__ ei,
                                           const float* __restrict__ dist,
                                           const uint16_t* __restrict__ Ybf,
                                           float* __restrict__ msg, int E) {
  int w = threadIdx.x >> 6, lane = threadIdx.x & 63;
  int base_e = (blockIdx.x * 4 + w) * 4;
  #pragma unroll
  for (int p = 0; p < 4; ++p) {
    int e = base_e + p;
    if (e >= E) break;
    int src = ei[e], dst = ei[E + e];
    float d = dist[e];
    int lo = (int)floorf(d * (1.0f / STEP_C)) - 1;
    lo = min(max(lo, 0), NG - NWIN);
    const uint16_t* yb = Ybf + (size_t)src * (NSLOT * UNITS) + lane;
    float tot = bfu(yb[NG * UNITS]);         // bias slot, weight 1
    #pragma unroll
    for (int l2 = 0; l2 < NWIN; ++l2) {
      float tt = d - (float)(lo + l2) * STEP_C;
      tot = fmaf(__expf(-GAMMA_C * tt * tt), bfu(yb[(lo + l2) * UNITS]), tot);
    }
    atomicAdd(&msg[dst * UNITS + lane], tot);
  }
}

// out = softplus(msg) - ln(2), numerically stable
__global__ void k_final(const float* __restrict__ msg, float* __restrict__ out, int n) {
  int i = blockIdx.x * 256 + threadIdx.x;
  if (i >= n) return;
  float x = msg[i];
  float sp = (x > 0.f) ? (x + log1pf(__expf(-x))) : log1pf(__expf(x));
  out[i] = sp - 0.69314718056f;
}

// ===== Fallback path (round-3 structure) if ws can't hold Y =====
__global__ void k_precompA_f(const float* __restrict__ W1, const float* __restrict__ b1,
                             const float* __restrict__ W2, const float* __restrict__ b2,
                             float* __restrict__ A) {
  int ij = blockIdx.x * 256 + threadIdx.x;
  int g = blockIdx.y;
  float acc = 0.f;
  if (g < NG) {
    const float* w1r = W1 + g * UNITS;
    #pragma unroll 8
    for (int k = 0; k < UNITS; ++k) acc = fmaf(w1r[k], W2[k * UU + ij], acc);
  } else {
    #pragma unroll 8
    for (int k = 0; k < UNITS; ++k) acc = fmaf(b1[k], W2[k * UU + ij], acc);
    acc += b2[ij];
  }
  A[g * UU + ij] = acc;
}

__global__ void k_precompT5_f(const float* __restrict__ A, const float* __restrict__ Wt,
                              uint16_t* __restrict__ T5B) {
  int idx = blockIdx.x * 256 + threadIdx.x;
  int g = blockIdx.y;
  int i = idx >> 6, m = idx & 63;
  const float* ar = A + g * UU + i * UNITS;
  const float* wr = Wt + m * UNITS;
  float acc = 0.f;
  #pragma unroll 8
  for (int j = 0; j < UNITS; ++j) acc = fmaf(ar[j], wr[j], acc);
  T5B[(((g << 3) + (m >> 3)) << 9) + (i << 3) + (m & 7)] = f2bf(acc);
}

#define ACC2(u, n0, n1) { a = fmaf(bf_lo(u), (n0), a); a = fmaf(bf_hi(u), (n1), a); }

__global__ void __launch_bounds__(256, 6) k_edge_f(
    const float* __restrict__ nf, const int* __restrict__ ei,
    const float* __restrict__ dist, const uint16_t* __restrict__ T5B,
    float* __restrict__ msg, int E) {
  __shared__ float nfs[4][UNITS];
  int w = threadIdx.x >> 6, lane = threadIdx.x & 63;
  int e = blockIdx.x * 4 + w;
  if (e >= E) return;
  int src = ei[e];
  int dst = ei[E + e];
  float d = dist[e];
  nfs[w][lane] = nf[src * UNITS + lane];
  int lo = (int)floorf(d * (1.0f / STEP_C)) - 1;
  lo = min(max(lo, 0), NG - NWIN);
  float df[NSL];
  #pragma unroll
  for (int l = 0; l < NWIN; ++l) {
    float t = d - (float)(lo + l) * STEP_C;
    df[l] = __expf(-GAMMA_C * t * t);
  }
  df[NWIN] = 1.0f;
  uint32_t off[NSL];
  #pragma unroll
  for (int l = 0; l < NSL; ++l) {
    int gg = (l < NWIN) ? (lo + l) : NG;
    off[l] = (uint32_t)((gg << 13) + (lane << 4));
  }
  const char* base = (const char*)T5B;
  float acc[NSL] = {0.f, 0.f, 0.f, 0.f, 0.f};
  #pragma unroll
  for (int mb = 0; mb < 8; ++mb) {
    float4 n0 = *reinterpret_cast<const float4*>(&nfs[w][mb * 8]);
    float4 n1 = *reinterpret_cast<const float4*>(&nfs[w][mb * 8 + 4]);
    #pragma unroll
    for (int l = 0; l < NSL; ++l) {
      uint4 u = *reinterpret_cast<const uint4*>(base + off[l] + (mb << 10));
      float a = acc[l];
      ACC2(u.x, n0.x, n0.y)
      ACC2(u.y, n0.z, n0.w)
      ACC2(u.z, n1.x, n1.y)
      ACC2(u.w, n1.z, n1.w)
      acc[l] = a;
    }
  }
  float tot = 0.f;
  #pragma unroll
  for (int l = 0; l < NSL; ++l) tot = fmaf(df[l], acc[l], tot);
  atomicAdd(&msg[dst * UNITS + lane], tot);
}

extern "C" void kernel_launch(void* const* d_in, const int* in_sizes, int n_in,
                              void* d_out, int out_size, void* d_ws, size_t ws_size,
                              hipStream_t stream) {
  const float* nf   = (const float*)d_in[0];
  const int*   ei   = (const int*)d_in[1];
  const float* dist = (const float*)d_in[2];
  const float* W1   = (const float*)d_in[3];
  const float* b1   = (const float*)d_in[4];
  const float* W2   = (const float*)d_in[5];
  const float* b2   = (const float*)d_in[6];
  const float* Wt   = (const float*)d_in[7];
  float* out = (float*)d_out;

  int E = in_sizes[2];               // 50000
  int NN = in_sizes[0] / UNITS;      // 10000
  int n_out = out_size;              // NN * UNITS

  // workspace layout: T5B @0, msg, Ybf (A only used by fallback, placed after msg)
  char* ws = (char*)d_ws;
  size_t off_msg = 417792;                                  // T5B: 51*4096*2
  size_t off_Y   = off_msg + (size_t)n_out * 4;             // msg
  size_t need    = off_Y + (size_t)NN * NSLOT * UNITS * 2;  // Ybf: ~65.3 MB

  uint16_t* T5B = (uint16_t*)ws;
  float*    msg = (float*)(ws + off_msg);

  if (ws_size >= need) {
    uint16_t* Ybf = (uint16_t*)(ws + off_Y);
    k_w <<<80, 256, 0, stream>>>(W1, b1, W2, b2, Wt, T5B, msg, n_out);
    k_y <<<dim3((NN + 127) / 128, 8), 256, 0, stream>>>(nf, T5B, Ybf, NN);
    k_e <<<(E + 15) / 16, 256, 0, stream>>>(ei, dist, Ybf, msg, E);
  } else {
    float* A = (float*)(ws + off_Y);         // fallback scratch (835584 B)
    hipMemsetAsync(msg, 0, (size_t)n_out * sizeof(float), stream);
    k_precompA_f <<<dim3(16, NSLOT), 256, 0, stream>>>(W1, b1, W2, b2, A);
    k_precompT5_f<<<dim3(16, NSLOT), 256, 0, stream>>>(A, Wt, T5B);
    k_edge_f     <<<(E + 3) / 4, 256, 0, stream>>>(nf, ei, dist, T5B, msg, E);
  }
  k_final <<<(n_out + 255) / 256, 256, 0, stream>>>(msg, out, n_out);
}

// Round 10
// 50.627 us; speedup vs baseline: 13.5630x; 3.3096x over previous
//
#include <hip/hip_runtime.h>
#include <stdint.h>

#define UNITS 64
#define UU 4096          // UNITS*UNITS
#define NG 50
#define NSLOT 51         // 50 gaussians + 1 bias slot
#define GAMMA_C 10.0f
#define STEP_C (30.0f / 49.0f)
#define NWIN 4           // gaussian window width (centers lo..lo+3)
#define NSL 5            // NWIN + bias slot

typedef __attribute__((ext_vector_type(8))) short bf16x8;
typedef __attribute__((ext_vector_type(4))) float f32x4;

__device__ __forceinline__ float bf_lo(uint32_t u) { return __uint_as_float(u << 16); }
__device__ __forceinline__ float bf_hi(uint32_t u) { return __uint_as_float(u & 0xffff0000u); }
__device__ __forceinline__ float bfu(uint16_t v) { return __uint_as_float(((uint32_t)v) << 16); }
__device__ __forceinline__ uint16_t f2bf(float x) {
  uint32_t u = __float_as_uint(x);
  u += 0x7fffu + ((u >> 16) & 1u);           // RNE to bf16
  return (uint16_t)(u >> 16);
}
__device__ __forceinline__ uint32_t pk_bf16(float lo, float hi) {
  uint32_t r;
  asm("v_cvt_pk_bf16_f32 %0, %1, %2" : "=v"(r) : "v"(lo), "v"(hi));
  return r;
}

// ===== k_at: wide fused A+T5 precompute =====
// Grid (16, 59). y=g<51, x=bx: block computes A[g, bx*256..+256) into LDS
// (64 FMA/thread, coalesced W2), then T5 rows gi=bx*4..+4 via Wt (staged in
// padded LDS, 2-way-conflict-free reads). y in [51,59): zero msg (128 blocks).
__global__ void __launch_bounds__(256) k_at(
    const float* __restrict__ W1, const float* __restrict__ b1,
    const float* __restrict__ W2, const float* __restrict__ b2,
    const float* __restrict__ Wt,
    uint16_t* __restrict__ T5B, float* __restrict__ msg, int n_out) {
  int g = blockIdx.y, bx = blockIdx.x;
  if (g >= NSLOT) {
    int n4 = n_out >> 2;
    float4 z = {0.f, 0.f, 0.f, 0.f};
    for (int t = ((g - NSLOT) * 16 + bx) * 256 + threadIdx.x; t < n4; t += 128 * 256)
      reinterpret_cast<float4*>(msg)[t] = z;
    return;
  }
  __shared__ float Aloc[256];                  // A[g, block's 256 ij]
  __shared__ float WtL[64 * 65];               // Wt padded: row stride 65
  const int t = threadIdx.x;
  const int ij = bx * 256 + t;

  // stage Wt (coalesced): thread t loads float4 chunks, scatter to padded rows
  #pragma unroll
  for (int q = 0; q < 4; ++q) {
    int idx = q * 256 + t;                     // [0,1024): float4 id in Wt
    float4 v = reinterpret_cast<const float4*>(Wt)[idx];
    int mm = idx >> 4, jj = (idx & 15) * 4;    // row m, col j
    float* dst = &WtL[mm * 65 + jj];
    dst[0] = v.x; dst[1] = v.y; dst[2] = v.z; dst[3] = v.w;
  }

  // phase A: A[g][ij] (64 FMA, W2 coalesced 256B/wave per k)
  {
    float acc = 0.f;
    if (g < NG) {
      const float* w1r = W1 + g * UNITS;
      #pragma unroll 8
      for (int k = 0; k < UNITS; ++k) acc = fmaf(w1r[k], W2[k * UU + ij], acc);
    } else {
      #pragma unroll 8
      for (int k = 0; k < UNITS; ++k) acc = fmaf(b1[k], W2[k * UU + ij], acc);
      acc += b2[ij];
    }
    Aloc[t] = acc;
  }
  __syncthreads();

  // phase B: T5[g, gi, m]; wave w owns i_local=w (Aloc read is wave-uniform
  // broadcast), lane owns m (WtL bank = (m+j)%32 -> 2-way = free)
  const int i_local = t >> 6, m = t & 63;
  const float* ar = &Aloc[i_local * 64];
  const float* wr = &WtL[m * 65];
  float acc = 0.f;
  #pragma unroll 8
  for (int j = 0; j < UNITS; ++j) acc = fmaf(ar[j], wr[j], acc);
  const int gi = bx * 4 + i_local;
  T5B[(((g << 3) + (m >> 3)) << 9) + (gi << 3) + (m & 7)] = f2bf(acc);
}

// ===== k_y: Y[node][g][ch] via MFMA; A-frags loaded once per block (f32->bf16
// in-register), g-loop reuses them. Permuted B cols: tile nt holds col 4*lr+nt,
// so lane stores 4 consecutive channels as one uint2. =====
__global__ void __launch_bounds__(256) k_y(const float* __restrict__ nf,
                                           const uint16_t* __restrict__ T5B,
                                           uint16_t* __restrict__ Ybf, int NN) {
  int w = threadIdx.x >> 6, l = threadIdx.x & 63;
  int lr = l & 15, lg = l >> 4;
  int gy = blockIdx.y;                       // 0..7
  int base = blockIdx.x * 128 + w * 32;

  // A fragments: lane l, row = node, k = kk*32 + lg*8 + j  (from f32, cvt here)
  union { bf16x8 v; uint32_t u[4]; } afr[2][2];
  #pragma unroll
  for (int ms = 0; ms < 2; ++ms) {
    int node = base + ms * 16 + lr;
    if (node >= NN) node = NN - 1;           // clamp: garbage rows never stored
    const float4* ab = reinterpret_cast<const float4*>(nf + node * UNITS) + lg * 2;
    #pragma unroll
    for (int kk = 0; kk < 2; ++kk) {
      float4 v0 = ab[kk * 8], v1 = ab[kk * 8 + 1];
      afr[ms][kk].u[0] = pk_bf16(v0.x, v0.y);
      afr[ms][kk].u[1] = pk_bf16(v0.z, v0.w);
      afr[ms][kk].u[2] = pk_bf16(v1.x, v1.y);
      afr[ms][kk].u[3] = pk_bf16(v1.z, v1.w);
    }
  }

  for (int g = gy; g < NSLOT; g += 8) {
    bf16x8 bfr[2][4];
    const char* bb = (const char*)T5B + (g << 13) + (lg << 10) + (lr << 6);
    #pragma unroll
    for (int kk = 0; kk < 2; ++kk)
      #pragma unroll
      for (int nt = 0; nt < 4; ++nt)
        bfr[kk][nt] = *reinterpret_cast<const bf16x8*>(bb + (kk << 12) + (nt << 4));

    f32x4 acc[2][4] = {};
    #pragma unroll
    for (int ms = 0; ms < 2; ++ms)
      #pragma unroll
      for (int kk = 0; kk < 2; ++kk)
        #pragma unroll
        for (int nt = 0; nt < 4; ++nt)
          acc[ms][nt] = __builtin_amdgcn_mfma_f32_16x16x32_bf16(afr[ms][kk].v, bfr[kk][nt],
                                                                acc[ms][nt], 0, 0, 0);

    #pragma unroll
    for (int ms = 0; ms < 2; ++ms) {
      #pragma unroll
      for (int q = 0; q < 4; ++q) {
        int node = base + ms * 16 + lg * 4 + q;
        if (node < NN) {
          uint2 p;
          p.x = pk_bf16(acc[ms][0][q], acc[ms][1][q]);
          p.y = pk_bf16(acc[ms][2][q], acc[ms][3][q]);
          uint16_t* yrow = Ybf + ((size_t)node * NSLOT + g) * UNITS;
          *reinterpret_cast<uint2*>(yrow + 4 * lr) = p;
        }
      }
    }
  }
}

// ===== k_e: 4 edges/wave; Y[node][g][ch] makes the 4 window reads 512B
// contiguous (+ adjacent bias row). =====
__global__ void __launch_bounds__(256) k_e(const int* __restrict__ ei,
                                           const float* __restrict__ dist,
                                           const uint16_t* __restrict__ Ybf,
                                           float* __restrict__ msg, int E) {
  int w = threadIdx.x >> 6, lane = threadIdx.x & 63;
  int base_e = (blockIdx.x * 4 + w) * 4;
  #pragma unroll
  for (int p = 0; p < 4; ++p) {
    int e = base_e + p;
    if (e >= E) break;
    int src = ei[e], dst = ei[E + e];
    float d = dist[e];
    int lo = (int)floorf(d * (1.0f / STEP_C)) - 1;
    lo = min(max(lo, 0), NG - NWIN);
    const uint16_t* yb = Ybf + (size_t)src * (NSLOT * UNITS) + lane;
    float tot = bfu(yb[NG * UNITS]);         // bias slot, weight 1
    #pragma unroll
    for (int l2 = 0; l2 < NWIN; ++l2) {
      float tt = d - (float)(lo + l2) * STEP_C;
      tot = fmaf(__expf(-GAMMA_C * tt * tt), bfu(yb[(lo + l2) * UNITS]), tot);
    }
    atomicAdd(&msg[dst * UNITS + lane], tot);
  }
}

// out = softplus(msg) - ln(2), numerically stable
__global__ void k_final(const float* __restrict__ msg, float* __restrict__ out, int n) {
  int i = blockIdx.x * 256 + threadIdx.x;
  if (i >= n) return;
  float x = msg[i];
  float sp = (x > 0.f) ? (x + log1pf(__expf(-x))) : log1pf(__expf(x));
  out[i] = sp - 0.69314718056f;
}

// ===== Fallback path (round-3 structure) if ws can't hold Y =====
__global__ void k_precompA_f(const float* __restrict__ W1, const float* __restrict__ b1,
                             const float* __restrict__ W2, const float* __restrict__ b2,
                             float* __restrict__ A) {
  int ij = blockIdx.x * 256 + threadIdx.x;
  int g = blockIdx.y;
  float acc = 0.f;
  if (g < NG) {
    const float* w1r = W1 + g * UNITS;
    #pragma unroll 8
    for (int k = 0; k < UNITS; ++k) acc = fmaf(w1r[k], W2[k * UU + ij], acc);
  } else {
    #pragma unroll 8
    for (int k = 0; k < UNITS; ++k) acc = fmaf(b1[k], W2[k * UU + ij], acc);
    acc += b2[ij];
  }
  A[g * UU + ij] = acc;
}

__global__ void k_precompT5_f(const float* __restrict__ A, const float* __restrict__ Wt,
                              uint16_t* __restrict__ T5B) {
  int idx = blockIdx.x * 256 + threadIdx.x;
  int g = blockIdx.y;
  int i = idx >> 6, m = idx & 63;
  const float* ar = A + g * UU + i * UNITS;
  const float* wr = Wt + m * UNITS;
  float acc = 0.f;
  #pragma unroll 8
  for (int j = 0; j < UNITS; ++j) acc = fmaf(ar[j], wr[j], acc);
  T5B[(((g << 3) + (m >> 3)) << 9) + (i << 3) + (m & 7)] = f2bf(acc);
}

#define ACC2(u, n0, n1) { a = fmaf(bf_lo(u), (n0), a); a = fmaf(bf_hi(u), (n1), a); }

__global__ void __launch_bounds__(256, 6) k_edge_f(
    const float* __restrict__ nf, const int* __restrict__ ei,
    const float* __restrict__ dist, const uint16_t* __restrict__ T5B,
    float* __restrict__ msg, int E) {
  __shared__ float nfs[4][UNITS];
  int w = threadIdx.x >> 6, lane = threadIdx.x & 63;
  int e = blockIdx.x * 4 + w;
  if (e >= E) return;
  int src = ei[e];
  int dst = ei[E + e];
  float d = dist[e];
  nfs[w][lane] = nf[src * UNITS + lane];
  int lo = (int)floorf(d * (1.0f / STEP_C)) - 1;
  lo = min(max(lo, 0), NG - NWIN);
  float df[NSL];
  #pragma unroll
  for (int l = 0; l < NWIN; ++l) {
    float t = d - (float)(lo + l) * STEP_C;
    df[l] = __expf(-GAMMA_C * t * t);
  }
  df[NWIN] = 1.0f;
  uint32_t off[NSL];
  #pragma unroll
  for (int l = 0; l < NSL; ++l) {
    int gg = (l < NWIN) ? (lo + l) : NG;
    off[l] = (uint32_t)((gg << 13) + (lane << 4));
  }
  const char* base = (const char*)T5B;
  float acc[NSL] = {0.f, 0.f, 0.f, 0.f, 0.f};
  #pragma unroll
  for (int mb = 0; mb < 8; ++mb) {
    float4 n0 = *reinterpret_cast<const float4*>(&nfs[w][mb * 8]);
    float4 n1 = *reinterpret_cast<const float4*>(&nfs[w][mb * 8 + 4]);
    #pragma unroll
    for (int l = 0; l < NSL; ++l) {
      uint4 u = *reinterpret_cast<const uint4*>(base + off[l] + (mb << 10));
      float a = acc[l];
      ACC2(u.x, n0.x, n0.y)
      ACC2(u.y, n0.z, n0.w)
      ACC2(u.z, n1.x, n1.y)
      ACC2(u.w, n1.z, n1.w)
      acc[l] = a;
    }
  }
  float tot = 0.f;
  #pragma unroll
  for (int l = 0; l < NSL; ++l) tot = fmaf(df[l], acc[l], tot);
  atomicAdd(&msg[dst * UNITS + lane], tot);
}

extern "C" void kernel_launch(void* const* d_in, const int* in_sizes, int n_in,
                              void* d_out, int out_size, void* d_ws, size_t ws_size,
                              hipStream_t stream) {
  const float* nf   = (const float*)d_in[0];
  const int*   ei   = (const int*)d_in[1];
  const float* dist = (const float*)d_in[2];
  const float* W1   = (const float*)d_in[3];
  const float* b1   = (const float*)d_in[4];
  const float* W2   = (const float*)d_in[5];
  const float* b2   = (const float*)d_in[6];
  const float* Wt   = (const float*)d_in[7];
  float* out = (float*)d_out;

  int E = in_sizes[2];               // 50000
  int NN = in_sizes[0] / UNITS;      // 10000
  int n_out = out_size;              // NN * UNITS

  // workspace layout: T5B @0, msg, Ybf (A only used by fallback, placed after msg)
  char* ws = (char*)d_ws;
  size_t off_msg = 417792;                                  // T5B: 51*4096*2
  size_t off_Y   = off_msg + (size_t)n_out * 4;             // msg
  size_t need    = off_Y + (size_t)NN * NSLOT * UNITS * 2;  // Ybf: ~65.3 MB

  uint16_t* T5B = (uint16_t*)ws;
  float*    msg = (float*)(ws + off_msg);

  if (ws_size >= need) {
    uint16_t* Ybf = (uint16_t*)(ws + off_Y);
    k_at<<<dim3(16, NSLOT + 8), 256, 0, stream>>>(W1, b1, W2, b2, Wt, T5B, msg, n_out);
    k_y <<<dim3((NN + 127) / 128, 8), 256, 0, stream>>>(nf, T5B, Ybf, NN);
    k_e <<<(E + 15) / 16, 256, 0, stream>>>(ei, dist, Ybf, msg, E);
  } else {
    float* A = (float*)(ws + off_Y);         // fallback scratch (835584 B)
    hipMemsetAsync(msg, 0, (size_t)n_out * sizeof(float), stream);
    k_precompA_f <<<dim3(16, NSLOT), 256, 0, stream>>>(W1, b1, W2, b2, A);
    k_precompT5_f<<<dim3(16, NSLOT), 256, 0, stream>>>(A, Wt, T5B);
    k_edge_f     <<<(E + 3) / 4, 256, 0, stream>>>(nf, ei, dist, T5B, msg, E);
  }
  k_final <<<(n_out + 255) / 256, 256, 0, stream>>>(msg, out, n_out);
}